// Round 1
// baseline (1569.076 us; speedup 1.0000x reference)
//
#include <hip/hip_runtime.h>
#include <float.h>

#define CDIM 256
#define NPTS 2048
#define MPTS 4096
#define NB   4
#define KNN  16

// ---------------------------------------------------------------- r2 kernel
__global__ __launch_bounds__(256) void r2_kernel(const float* __restrict__ feat,
                                                 const float* __restrict__ featdb,
                                                 float* __restrict__ r2) {
    int g = blockIdx.x * 256 + threadIdx.x;     // 0..16383 = b*4096+m
    int b = g >> 12, m = g & 4095;
    const float* base = (m < NPTS) ? (feat + (size_t)b * CDIM * NPTS + m)
                                   : (featdb + (size_t)b * CDIM * NPTS + (m - NPTS));
    float acc = 0.f;
    for (int c = 0; c < CDIM; ++c) {
        float v = base[(size_t)c * NPTS];
        acc += v * v;
    }
    r2[g] = acc;
}

// ------------------------------------------------------ score GEMM (fp32)
// S[n - n0][m] = r2[m] - 2 * dot(feat[b,:,n], fusion[b,:,m])
// 128x128 tile, 8x8 micro-tile, K=256 in steps of 32.
__global__ __launch_bounds__(256) void score_gemm(const float* __restrict__ feat,
                                                  const float* __restrict__ featdb,
                                                  const float* __restrict__ r2,
                                                  float* __restrict__ S,
                                                  int b, int n0) {
    __shared__ float As[32][128];
    __shared__ float Bs[32][128];
    int tid = threadIdx.x;
    int nbase = n0 + blockIdx.x * 128;
    int mbase = blockIdx.y * 128;
    const float* A = feat + (size_t)b * CDIM * NPTS + nbase;   // A[c*2048 + dn]
    const float* Bp = (mbase < NPTS)
                          ? (feat + (size_t)b * CDIM * NPTS + mbase)
                          : (featdb + (size_t)b * CDIM * NPTS + (mbase - NPTS));
    int tx = tid & 15, ty = tid >> 4;
    float acc[8][8];
#pragma unroll
    for (int i = 0; i < 8; i++)
#pragma unroll
        for (int j = 0; j < 8; j++) acc[i][j] = 0.f;

    for (int k0 = 0; k0 < CDIM; k0 += 32) {
#pragma unroll
        for (int i = 0; i < 4; i++) {
            int e = tid + i * 256;        // float4 slot 0..1023
            int c = e >> 5, x = e & 31;   // 32 float4 per 128-wide row
            reinterpret_cast<float4&>(As[c][x * 4]) =
                *reinterpret_cast<const float4*>(A + (size_t)(k0 + c) * NPTS + x * 4);
            reinterpret_cast<float4&>(Bs[c][x * 4]) =
                *reinterpret_cast<const float4*>(Bp + (size_t)(k0 + c) * NPTS + x * 4);
        }
        __syncthreads();
#pragma unroll
        for (int c = 0; c < 32; c++) {
            float a[8], bv[8];
            *reinterpret_cast<float4*>(a)     = reinterpret_cast<float4&>(As[c][ty * 8]);
            *reinterpret_cast<float4*>(a + 4) = reinterpret_cast<float4&>(As[c][ty * 8 + 4]);
            *reinterpret_cast<float4*>(bv)     = reinterpret_cast<float4&>(Bs[c][tx * 8]);
            *reinterpret_cast<float4*>(bv + 4) = reinterpret_cast<float4&>(Bs[c][tx * 8 + 4]);
#pragma unroll
            for (int i = 0; i < 8; i++)
#pragma unroll
                for (int j = 0; j < 8; j++) acc[i][j] += a[i] * bv[j];
        }
        __syncthreads();
    }
    const float* r2b = r2 + b * MPTS + mbase;
    float rr[8];
#pragma unroll
    for (int j = 0; j < 8; j++) rr[j] = r2b[tx * 8 + j];
#pragma unroll
    for (int i = 0; i < 8; i++) {
        int row = blockIdx.x * 128 + ty * 8 + i;   // row within chunk
        float* dst = S + (size_t)row * MPTS + mbase + tx * 8;
#pragma unroll
        for (int j = 0; j < 8; j++) dst[j] = rr[j] - 2.f * acc[i][j];
    }
}

// ------------------------------------------------------------- top-16 select
// One block per query row; 16 iterations of parallel argmin. Only the SET of
// indices matters downstream (softmax+sum over k are permutation invariant).
__global__ __launch_bounds__(256) void topk16(const float* __restrict__ S,
                                              int* __restrict__ idxout,
                                              int b, int n0) {
    __shared__ float sv[4096];
    __shared__ float rv[256];
    __shared__ int ri[256];
    __shared__ int res[16];
    int tid = threadIdx.x;
    const float* row = S + (size_t)blockIdx.x * MPTS;
#pragma unroll
    for (int i = 0; i < 16; i++) sv[tid + i * 256] = row[tid + i * 256];
    __syncthreads();
    for (int it = 0; it < 16; ++it) {
        float best = FLT_MAX;
        int bi = MPTS;
#pragma unroll
        for (int i = 0; i < 16; i++) {
            int m = tid + i * 256;
            float v = sv[m];
            if (v < best) { best = v; bi = m; }   // ascending m: ties keep lowest idx
        }
        rv[tid] = best; ri[tid] = bi;
        __syncthreads();
        if (tid < 64) {
            float v = rv[tid];
            int mi = ri[tid];
#pragma unroll
            for (int j = 1; j < 4; j++) {
                float v2 = rv[tid + j * 64];
                int i2 = ri[tid + j * 64];
                if (v2 < v || (v2 == v && i2 < mi)) { v = v2; mi = i2; }
            }
#pragma unroll
            for (int off = 32; off; off >>= 1) {
                float v2 = __shfl_down(v, off);
                int i2 = __shfl_down(mi, off);
                if (v2 < v || (v2 == v && i2 < mi)) { v = v2; mi = i2; }
            }
            if (tid == 0) { res[it] = mi; sv[mi] = FLT_MAX; }
        }
        __syncthreads();
    }
    if (tid < 16) idxout[((size_t)(b * NPTS + n0 + blockIdx.x)) * KNN + tid] = res[tid];
}

// ---------------------------------------------------------------- fused MLP
// One block per (b, n). LDS holds [c][k] tiles with stride 16; GEMM reads are
// wave-uniform (LDS broadcast); writes go through float4 (8-way max conflict).
__device__ __forceinline__ void row_gemm16(const float* __restrict__ wrow, int kc,
                                           const float* __restrict__ xlds,
                                           float bias, float* __restrict__ acc) {
#pragma unroll
    for (int j = 0; j < 16; j++) acc[j] = bias;
    for (int c = 0; c < kc; c += 4) {
        float4 w4 = *reinterpret_cast<const float4*>(wrow + c);
        const float* xc = xlds + c * 16;
#pragma unroll
        for (int j = 0; j < 16; j++) acc[j] += w4.x * xc[j];
#pragma unroll
        for (int j = 0; j < 16; j++) acc[j] += w4.y * xc[16 + j];
#pragma unroll
        for (int j = 0; j < 16; j++) acc[j] += w4.z * xc[32 + j];
#pragma unroll
        for (int j = 0; j < 16; j++) acc[j] += w4.w * xc[48 + j];
    }
}

__device__ __forceinline__ void store16(float* __restrict__ dst, const float* __restrict__ v) {
#pragma unroll
    for (int q = 0; q < 4; q++) {
        float4 f = make_float4(v[4 * q], v[4 * q + 1], v[4 * q + 2], v[4 * q + 3]);
        *reinterpret_cast<float4*>(dst + 4 * q) = f;
    }
}

__global__ __launch_bounds__(256) void fused_mlp(
    const float* __restrict__ pcd, const float* __restrict__ feat,
    const float* __restrict__ pcddb, const float* __restrict__ featdb,
    const int* __restrict__ knn,
    const float* __restrict__ pw1, const float* __restrict__ pb1,
    const float* __restrict__ pg, const float* __restrict__ pbe,
    const float* __restrict__ pm, const float* __restrict__ pv,
    const float* __restrict__ pw2, const float* __restrict__ pb2,
    const float* __restrict__ aw1, const float* __restrict__ ab1,
    const float* __restrict__ ag, const float* __restrict__ abe,
    const float* __restrict__ am, const float* __restrict__ av,
    const float* __restrict__ aw2, const float* __restrict__ ab2,
    float* __restrict__ out) {
    __shared__ float gf[CDIM * 16];
    __shared__ float pe[CDIM * 16];
    __shared__ float xb[CDIM * 16];
    __shared__ float h[64 * 16];
    __shared__ float pr[3 * 16];
    __shared__ int sidx[16];

    int t = threadIdx.x;
    int bn = blockIdx.x;
    int b = bn >> 11, n = bn & 2047;
    const float* ff  = feat + (size_t)b * CDIM * NPTS;
    const float* ffd = featdb + (size_t)b * CDIM * NPTS;

    if (t < 16) sidx[t] = knn[(size_t)bn * KNN + t];
    __syncthreads();

    // gather group_feat row t (c = t)
    float fv = ff[(size_t)t * NPTS + n];
    float g[16];
#pragma unroll
    for (int j = 0; j < 16; j++) {
        int m = sidx[j];
        g[j] = (m < NPTS) ? ff[(size_t)t * NPTS + m] : ffd[(size_t)t * NPTS + (m - NPTS)];
    }
    store16(gf + t * 16, g);

    if (t < 48) {
        int c = t >> 4, j = t & 15;
        int m = sidx[j];
        const float* pp  = pcd + (size_t)b * 3 * NPTS + (size_t)c * NPTS;
        const float* ppd = pcddb + (size_t)b * 3 * NPTS + (size_t)c * NPTS;
        float gp = (m < NPTS) ? pp[m] : ppd[m - NPTS];
        pr[c * 16 + j] = pp[n] - gp;
    }
    __syncthreads();

    // pos hidden: 64x16 outputs, 4 per thread
    for (int e = t; e < 1024; e += 256) {
        int o = e >> 4, j = e & 15;
        float val = pw1[o * 3] * pr[j] + pw1[o * 3 + 1] * pr[16 + j] +
                    pw1[o * 3 + 2] * pr[32 + j] + pb1[o];
        float inv = pg[o] / sqrtf(pv[o] + 1e-5f);
        val = val * inv + (pbe[o] - pm[o] * inv);
        h[e] = fmaxf(val, 0.f);
    }
    __syncthreads();

    // pos_embedding row t
    float acc[16];
    row_gemm16(pw2 + (size_t)t * 64, 64, h, pb2[t], acc);
    store16(pe + t * 16, acc);
    __syncthreads();

    // x = feat - group_feat + pos_embedding (row t)
    {
        float xr[16];
#pragma unroll
        for (int j = 0; j < 16; j++) xr[j] = fv - gf[t * 16 + j] + pe[t * 16 + j];
        store16(xb + t * 16, xr);
    }
    __syncthreads();

    // attn layer 1: relu(bn(aw1 @ x + ab1)), row t; overwrite xb after sync
    row_gemm16(aw1 + (size_t)t * 256, 256, xb, ab1[t], acc);
    {
        float inv = ag[t] / sqrtf(av[t] + 1e-5f);
        float sh = abe[t] - am[t] * inv;
        float a1[16];
#pragma unroll
        for (int j = 0; j < 16; j++) a1[j] = fmaxf(acc[j] * inv + sh, 0.f);
        __syncthreads();               // all done reading xb
        store16(xb + t * 16, a1);
    }
    __syncthreads();

    // attn layer 2 + softmax + weighted sum, row t
    row_gemm16(aw2 + (size_t)t * 256, 256, xb, ab2[t], acc);
    {
        float mx = acc[0];
#pragma unroll
        for (int j = 1; j < 16; j++) mx = fmaxf(mx, acc[j]);
        float s = 0.f;
#pragma unroll
        for (int j = 0; j < 16; j++) { acc[j] = __expf(acc[j] - mx); s += acc[j]; }
        float r = 1.f / s;
        float o = 0.f;
#pragma unroll
        for (int q = 0; q < 4; q++) {
            float4 gq = *reinterpret_cast<const float4*>(gf + t * 16 + 4 * q);
            float4 pq = *reinterpret_cast<const float4*>(pe + t * 16 + 4 * q);
            o += acc[4 * q + 0] * (gq.x + pq.x);
            o += acc[4 * q + 1] * (gq.y + pq.y);
            o += acc[4 * q + 2] * (gq.z + pq.z);
            o += acc[4 * q + 3] * (gq.w + pq.w);
        }
        out[(size_t)b * CDIM * NPTS + (size_t)t * NPTS + n] = o * r;
    }
}

// ------------------------------------------------------------------- launch
extern "C" void kernel_launch(void* const* d_in, const int* in_sizes, int n_in,
                              void* d_out, int out_size, void* d_ws, size_t ws_size,
                              hipStream_t stream) {
    const float* pcd    = (const float*)d_in[0];
    const float* feat   = (const float*)d_in[1];
    const float* pcddb  = (const float*)d_in[2];
    const float* featdb = (const float*)d_in[3];
    const float* pw1 = (const float*)d_in[4];
    const float* pb1 = (const float*)d_in[5];
    const float* pg  = (const float*)d_in[6];
    const float* pbe = (const float*)d_in[7];
    const float* pm  = (const float*)d_in[8];
    const float* pv  = (const float*)d_in[9];
    const float* pw2 = (const float*)d_in[10];
    const float* pb2 = (const float*)d_in[11];
    const float* aw1 = (const float*)d_in[12];
    const float* ab1 = (const float*)d_in[13];
    const float* ag  = (const float*)d_in[14];
    const float* abe = (const float*)d_in[15];
    const float* am  = (const float*)d_in[16];
    const float* av  = (const float*)d_in[17];
    const float* aw2 = (const float*)d_in[18];
    const float* ab2 = (const float*)d_in[19];
    float* out = (float*)d_out;

    char* ws = (char*)d_ws;
    float* ws_r2 = (float*)ws;                       // 16384 floats = 64 KB
    int* ws_idx  = (int*)(ws + 65536);               // 131072 ints = 512 KB
    float* ws_s  = (float*)(ws + 65536 + 524288);    // chunk*4096 floats

    size_t fixed = 65536 + 524288;
    size_t avail = (ws_size > fixed) ? ws_size - fixed : 0;
    int chunk = 256;
    if (avail >= (size_t)2048 * 4096 * 4) chunk = 2048;
    else if (avail >= (size_t)1024 * 4096 * 4) chunk = 1024;
    else if (avail >= (size_t)512 * 4096 * 4) chunk = 512;

    r2_kernel<<<64, 256, 0, stream>>>(feat, featdb, ws_r2);
    for (int b = 0; b < NB; ++b) {
        for (int n0 = 0; n0 < NPTS; n0 += chunk) {
            dim3 g(chunk / 128, MPTS / 128);
            score_gemm<<<g, 256, 0, stream>>>(feat, featdb, ws_r2, ws_s, b, n0);
            topk16<<<chunk, 256, 0, stream>>>(ws_s, ws_idx, b, n0);
        }
    }
    fused_mlp<<<NB * NPTS, 256, 0, stream>>>(pcd, feat, pcddb, featdb, ws_idx,
                                             pw1, pb1, pg, pbe, pm, pv, pw2, pb2,
                                             aw1, ab1, ag, abe, am, av, aw2, ab2, out);
}

// Round 2
// 550.364 us; speedup vs baseline: 2.8510x; 2.8510x over previous
//
#include <hip/hip_runtime.h>
#include <float.h>

#define CDIM 256
#define NPTS 2048
#define MPTS 4096
#define NB   4
#define KNN  16
#define NPB  8      // query points per fused block
#define COLS 128    // NPB * KNN

typedef short  short8 __attribute__((ext_vector_type(8)));
typedef __bf16 bf16x8 __attribute__((ext_vector_type(8)));
typedef float  f32x4  __attribute__((ext_vector_type(4)));

__device__ __forceinline__ unsigned short f2b(float f) {
    unsigned u = __float_as_uint(f);
    unsigned r = (u + 0x7FFFu + ((u >> 16) & 1u)) >> 16;
    return (unsigned short)r;
}
__device__ __forceinline__ float b2f(unsigned short h) {
    return __uint_as_float(((unsigned)h) << 16);
}
__device__ __forceinline__ bf16x8 as_bf(short8 s) {
    union { short8 a; bf16x8 b; } u; u.a = s; return u.b;
}
// swizzled byte offsets: row stride 512B / 128B, XOR col&7 into bits 4-6
__device__ __forceinline__ int swz512(int col, int byte) {
    return col * 512 + (byte ^ ((col & 7) << 4));
}
__device__ __forceinline__ int swz128(int col, int byte) {
    return col * 128 + (byte ^ ((col & 7) << 4));
}

// ---------------------------------------------------------------- r2 kernel
__global__ __launch_bounds__(256) void r2_kernel(const float* __restrict__ feat,
                                                 const float* __restrict__ featdb,
                                                 float* __restrict__ r2) {
    int g = blockIdx.x * 256 + threadIdx.x;     // b*4096+m
    int b = g >> 12, m = g & 4095;
    const float* base = (m < NPTS) ? (feat + (size_t)b * CDIM * NPTS + m)
                                   : (featdb + (size_t)b * CDIM * NPTS + (m - NPTS));
    float acc = 0.f;
    for (int c = 0; c < CDIM; ++c) {
        float v = base[(size_t)c * NPTS];
        acc += v * v;
    }
    r2[g] = acc;
}

// ------------------------------------------------------ score GEMM (fp32, exact KNN)
__global__ __launch_bounds__(256) void score_gemm(const float* __restrict__ feat,
                                                  const float* __restrict__ featdb,
                                                  const float* __restrict__ r2,
                                                  float* __restrict__ S,
                                                  int b, int n0) {
    __shared__ float As[32][128];
    __shared__ float Bs[32][128];
    int tid = threadIdx.x;
    int nbase = n0 + blockIdx.x * 128;
    int mbase = blockIdx.y * 128;
    const float* A = feat + (size_t)b * CDIM * NPTS + nbase;
    const float* Bp = (mbase < NPTS)
                          ? (feat + (size_t)b * CDIM * NPTS + mbase)
                          : (featdb + (size_t)b * CDIM * NPTS + (mbase - NPTS));
    int tx = tid & 15, ty = tid >> 4;
    float acc[8][8];
#pragma unroll
    for (int i = 0; i < 8; i++)
#pragma unroll
        for (int j = 0; j < 8; j++) acc[i][j] = 0.f;

    for (int k0 = 0; k0 < CDIM; k0 += 32) {
#pragma unroll
        for (int i = 0; i < 4; i++) {
            int e = tid + i * 256;
            int c = e >> 5, x = e & 31;
            reinterpret_cast<float4&>(As[c][x * 4]) =
                *reinterpret_cast<const float4*>(A + (size_t)(k0 + c) * NPTS + x * 4);
            reinterpret_cast<float4&>(Bs[c][x * 4]) =
                *reinterpret_cast<const float4*>(Bp + (size_t)(k0 + c) * NPTS + x * 4);
        }
        __syncthreads();
#pragma unroll
        for (int c = 0; c < 32; c++) {
            float a[8], bv[8];
            *reinterpret_cast<float4*>(a)     = reinterpret_cast<float4&>(As[c][ty * 8]);
            *reinterpret_cast<float4*>(a + 4) = reinterpret_cast<float4&>(As[c][ty * 8 + 4]);
            *reinterpret_cast<float4*>(bv)     = reinterpret_cast<float4&>(Bs[c][tx * 8]);
            *reinterpret_cast<float4*>(bv + 4) = reinterpret_cast<float4&>(Bs[c][tx * 8 + 4]);
#pragma unroll
            for (int i = 0; i < 8; i++)
#pragma unroll
                for (int j = 0; j < 8; j++) acc[i][j] += a[i] * bv[j];
        }
        __syncthreads();
    }
    const float* r2b = r2 + b * MPTS + mbase;
    float rr[8];
#pragma unroll
    for (int j = 0; j < 8; j++) rr[j] = r2b[tx * 8 + j];
#pragma unroll
    for (int i = 0; i < 8; i++) {
        int row = blockIdx.x * 128 + ty * 8 + i;
        float* dst = S + (size_t)row * MPTS + mbase + tx * 8;
#pragma unroll
        for (int j = 0; j < 8; j++) dst[j] = rr[j] - 2.f * acc[i][j];
    }
}

// ------------------------------------------------------------- top-16 select
__global__ __launch_bounds__(256) void topk16(const float* __restrict__ S,
                                              int* __restrict__ idxout,
                                              int b, int n0) {
    __shared__ float sv[4096];
    __shared__ float rv[256];
    __shared__ int ri[256];
    __shared__ int res[16];
    int tid = threadIdx.x;
    const float* row = S + (size_t)blockIdx.x * MPTS;
#pragma unroll
    for (int i = 0; i < 16; i++) sv[tid + i * 256] = row[tid + i * 256];
    __syncthreads();
    for (int it = 0; it < 16; ++it) {
        float best = FLT_MAX;
        int bi = MPTS;
#pragma unroll
        for (int i = 0; i < 16; i++) {
            int m = tid + i * 256;
            float v = sv[m];
            if (v < best) { best = v; bi = m; }
        }
        rv[tid] = best; ri[tid] = bi;
        __syncthreads();
        if (tid < 64) {
            float v = rv[tid];
            int mi = ri[tid];
#pragma unroll
            for (int j = 1; j < 4; j++) {
                float v2 = rv[tid + j * 64];
                int i2 = ri[tid + j * 64];
                if (v2 < v || (v2 == v && i2 < mi)) { v = v2; mi = i2; }
            }
#pragma unroll
            for (int off = 32; off; off >>= 1) {
                float v2 = __shfl_down(v, off);
                int i2 = __shfl_down(mi, off);
                if (v2 < v || (v2 == v && i2 < mi)) { v = v2; mi = i2; }
            }
            if (tid == 0) { res[it] = mi; sv[mi] = FLT_MAX; }
        }
        __syncthreads();
    }
    if (tid < 16) idxout[((size_t)(b * NPTS + n0 + blockIdx.x)) * KNN + tid] = res[tid];
}

// ------------------------------------------- weights fp32 -> bf16 conversion
__global__ __launch_bounds__(256) void wcvt(const float* __restrict__ aw1,
                                            const float* __restrict__ aw2,
                                            const float* __restrict__ pw2,
                                            short* __restrict__ aw1b,
                                            short* __restrict__ aw2b,
                                            short* __restrict__ pw2b) {
    int i = blockIdx.x * 256 + threadIdx.x;
    if (i < 256 * 256) {
        aw1b[i] = (short)f2b(aw1[i]);
        aw2b[i] = (short)f2b(aw2[i]);
    }
    if (i < 256 * 64) pw2b[i] = (short)f2b(pw2[i]);
}

// --------------------------- fusion_feat (B,C,M) -> featT (B,M,C) bf16
__global__ __launch_bounds__(256) void tposeT(const float* __restrict__ feat,
                                              const float* __restrict__ featdb,
                                              short* __restrict__ featT) {
    int b = blockIdx.y;
    int m = blockIdx.x * 256 + threadIdx.x;
    const float* src = (m < NPTS) ? (feat + (size_t)b * CDIM * NPTS + m)
                                  : (featdb + (size_t)b * CDIM * NPTS + (m - NPTS));
    short* dst = featT + ((size_t)b * MPTS + m) * CDIM;
    for (int c0 = 0; c0 < CDIM; c0 += 8) {
        short8 v;
#pragma unroll
        for (int i = 0; i < 8; i++) v[i] = (short)f2b(src[(size_t)(c0 + i) * NPTS]);
        *(short8*)(dst + c0) = v;
    }
}

// ---------------------------------------------------------------- fused MFMA MLP
// One block = 8 query points = 128 MFMA columns (n-major, k-minor).
// pos MLP layer2 + attn layer1 + attn layer2 on mfma_f32_16x16x32_bf16.
// ab2 dropped: constant-per-(c,n) bias cancels in softmax over k.
__global__ __launch_bounds__(512) void fused_mlp2(
    const float* __restrict__ pcd, const float* __restrict__ pcddb,
    const short* __restrict__ featT, const int* __restrict__ knn,
    const float* __restrict__ pw1, const float* __restrict__ pb1,
    const float* __restrict__ pg, const float* __restrict__ pbe,
    const float* __restrict__ pm, const float* __restrict__ pv,
    const short* __restrict__ pw2b, const float* __restrict__ pb2,
    const short* __restrict__ aw1b, const float* __restrict__ ab1,
    const float* __restrict__ ag, const float* __restrict__ abe,
    const float* __restrict__ am, const float* __restrict__ av,
    const short* __restrict__ aw2b,
    float* __restrict__ out) {
    __shared__ __align__(16) short xbuf[COLS * 256];   // 64 KB: x, then a1 [col][k]
    __shared__ __align__(16) short pebuf[COLS * 256];  // 64 KB: pe [col][c]
    __shared__ __align__(16) short hbuf[COLS * 64];    // 16 KB: h  [col][o]
    __shared__ float pr[3][COLS];
    __shared__ int   sidx[COLS];
    __shared__ float ainv[256], ash2[256];
    __shared__ float pinv[64], psh[64];

    const int tid  = threadIdx.x;
    const int lane = tid & 63;
    const int wave = tid >> 6;
    const int l15  = lane & 15, l4 = lane >> 4;
    const int blk  = blockIdx.x;
    const int b    = blk >> 8;
    const int n0   = (blk & 255) * NPB;
    const int R0   = wave * 32;
    const int kfr  = l4 * 8;

    if (tid < COLS) {
        sidx[tid] = knn[((size_t)(b * NPTS + n0 + (tid >> 4))) * KNN + (tid & 15)];
    } else if (tid < COLS + 256) {
        int c = tid - COLS;
        float inv = ag[c] / sqrtf(av[c] + 1e-5f);
        ainv[c] = inv;
        ash2[c] = abe[c] - am[c] * inv + ab1[c] * inv;   // bias folded pre-BN
    } else if (tid < COLS + 256 + 64) {
        int o = tid - COLS - 256;
        float inv = pg[o] / sqrtf(pv[o] + 1e-5f);
        pinv[o] = inv;
        psh[o] = pbe[o] - pm[o] * inv;
    }
    __syncthreads();

    // pos_rel (3 x 128), gathered from fp32 pcd
    if (tid < 3 * COLS) {
        int c = tid >> 7, col = tid & (COLS - 1);
        int m = sidx[col];
        const float* pc  = pcd + ((size_t)b * 3 + c) * NPTS;
        const float* pcx = pcddb + ((size_t)b * 3 + c) * NPTS;
        float gp = (m < NPTS) ? pc[m] : pcx[m - NPTS];
        pr[c][col] = pc[n0 + (col >> 4)] - gp;
    }
    __syncthreads();

    // h = relu(bn(pw1 @ pos_rel + pb1)) : stored [col][64 o] bf16
    {
        int col = tid >> 2, o0 = (tid & 3) * 16;
        float x0 = pr[0][col], x1 = pr[1][col], x2 = pr[2][col];
        short8 h0, h1;
#pragma unroll
        for (int i = 0; i < 16; i++) {
            int o = o0 + i;
            float v = pw1[o * 3] * x0 + pw1[o * 3 + 1] * x1 + pw1[o * 3 + 2] * x2 + pb1[o];
            v = fmaxf(v * pinv[o] + psh[o], 0.f);
            if (i < 8) h0[i] = (short)f2b(v); else h1[i - 8] = (short)f2b(v);
        }
        *(short8*)((char*)hbuf + swz128(col, o0 * 2))      = h0;
        *(short8*)((char*)hbuf + swz128(col, o0 * 2 + 16)) = h1;
    }
    __syncthreads();

    f32x4 acc[2][8];
#pragma unroll
    for (int rt = 0; rt < 2; rt++)
#pragma unroll
        for (int ct = 0; ct < 8; ct++) acc[rt][ct] = (f32x4){0.f, 0.f, 0.f, 0.f};

    // ---- pe GEMM: pw2 (256x64) @ h (64x128) ----
#pragma unroll
    for (int ks = 0; ks < 2; ks++) {
        int k0 = ks * 32 + kfr;
        bf16x8 a0 = as_bf(*(const short8*)(pw2b + (size_t)(R0 + l15) * 64 + k0));
        bf16x8 a1 = as_bf(*(const short8*)(pw2b + (size_t)(R0 + 16 + l15) * 64 + k0));
#pragma unroll
        for (int ct = 0; ct < 8; ct++) {
            bf16x8 bb = as_bf(*(const short8*)((char*)hbuf + swz128(ct * 16 + l15, k0 * 2)));
            acc[0][ct] = __builtin_amdgcn_mfma_f32_16x16x32_bf16(a0, bb, acc[0][ct], 0, 0, 0);
            acc[1][ct] = __builtin_amdgcn_mfma_f32_16x16x32_bf16(a1, bb, acc[1][ct], 0, 0, 0);
        }
    }
#pragma unroll
    for (int rt = 0; rt < 2; rt++) {
        int cb = R0 + rt * 16 + 4 * l4;
        float4 pb = *(const float4*)(pb2 + cb);
        float pbv[4] = {pb.x, pb.y, pb.z, pb.w};
#pragma unroll
        for (int ct = 0; ct < 8; ct++) {
            int col = ct * 16 + l15;
#pragma unroll
            for (int r = 0; r < 4; r++)
                *(short*)((char*)pebuf + swz512(col, (cb + r) * 2)) =
                    (short)f2b(acc[rt][ct][r] + pbv[r]);
        }
    }
    __syncthreads();

    // ---- x = feat[n] - gf[m] + pe : [col][256 k] bf16 ----
    {
        int col = tid & (COLS - 1);
        int m = sidx[col];
        const short* fTm = featT + ((size_t)(b * MPTS) + m) * CDIM;
        const short* fTn = featT + ((size_t)(b * MPTS) + n0 + (col >> 4)) * CDIM;
        int c0 = (tid >> 7) * 64;
#pragma unroll
        for (int cc = 0; cc < 64; cc += 8) {
            int c = c0 + cc;
            short8 fm = *(const short8*)(fTm + c);
            short8 fn = *(const short8*)(fTn + c);
            short8 pe = *(const short8*)((char*)pebuf + swz512(col, c * 2));
            short8 xv;
#pragma unroll
            for (int i = 0; i < 8; i++)
                xv[i] = (short)f2b(b2f((unsigned short)fn[i]) - b2f((unsigned short)fm[i]) +
                                   b2f((unsigned short)pe[i]));
            *(short8*)((char*)xbuf + swz512(col, c * 2)) = xv;
        }
    }
    __syncthreads();

    // ---- GEMM1: aw1 (256x256) @ x ----
#pragma unroll
    for (int rt = 0; rt < 2; rt++)
#pragma unroll
        for (int ct = 0; ct < 8; ct++) acc[rt][ct] = (f32x4){0.f, 0.f, 0.f, 0.f};
#pragma unroll
    for (int ks = 0; ks < 8; ks++) {
        int k0 = ks * 32 + kfr;
        bf16x8 a0 = as_bf(*(const short8*)(aw1b + (size_t)(R0 + l15) * 256 + k0));
        bf16x8 a1 = as_bf(*(const short8*)(aw1b + (size_t)(R0 + 16 + l15) * 256 + k0));
#pragma unroll
        for (int ct = 0; ct < 8; ct++) {
            bf16x8 bb = as_bf(*(const short8*)((char*)xbuf + swz512(ct * 16 + l15, k0 * 2)));
            acc[0][ct] = __builtin_amdgcn_mfma_f32_16x16x32_bf16(a0, bb, acc[0][ct], 0, 0, 0);
            acc[1][ct] = __builtin_amdgcn_mfma_f32_16x16x32_bf16(a1, bb, acc[1][ct], 0, 0, 0);
        }
    }
    __syncthreads();   // all waves done reading xbuf
    // a1 = relu(acc*ainv + ash2) -> xbuf [col][c]
#pragma unroll
    for (int rt = 0; rt < 2; rt++) {
        int cb = R0 + rt * 16 + 4 * l4;
        float iv[4], sh[4];
#pragma unroll
        for (int r = 0; r < 4; r++) { iv[r] = ainv[cb + r]; sh[r] = ash2[cb + r]; }
#pragma unroll
        for (int ct = 0; ct < 8; ct++) {
            int col = ct * 16 + l15;
#pragma unroll
            for (int r = 0; r < 4; r++) {
                float v = fmaxf(acc[rt][ct][r] * iv[r] + sh[r], 0.f);
                *(short*)((char*)xbuf + swz512(col, (cb + r) * 2)) = (short)f2b(v);
            }
        }
    }
    __syncthreads();

    // ---- GEMM2: aw2 (256x256) @ a1 ----
#pragma unroll
    for (int rt = 0; rt < 2; rt++)
#pragma unroll
        for (int ct = 0; ct < 8; ct++) acc[rt][ct] = (f32x4){0.f, 0.f, 0.f, 0.f};
#pragma unroll
    for (int ks = 0; ks < 8; ks++) {
        int k0 = ks * 32 + kfr;
        bf16x8 a0 = as_bf(*(const short8*)(aw2b + (size_t)(R0 + l15) * 256 + k0));
        bf16x8 a1 = as_bf(*(const short8*)(aw2b + (size_t)(R0 + 16 + l15) * 256 + k0));
#pragma unroll
        for (int ct = 0; ct < 8; ct++) {
            bf16x8 bb = as_bf(*(const short8*)((char*)xbuf + swz512(ct * 16 + l15, k0 * 2)));
            acc[0][ct] = __builtin_amdgcn_mfma_f32_16x16x32_bf16(a0, bb, acc[0][ct], 0, 0, 0);
            acc[1][ct] = __builtin_amdgcn_mfma_f32_16x16x32_bf16(a1, bb, acc[1][ct], 0, 0, 0);
        }
    }

    // ---- softmax over 16 k (16-lane groups) + weighted sum -> out ----
#pragma unroll
    for (int rt = 0; rt < 2; rt++) {
        int cb = R0 + rt * 16 + 4 * l4;
#pragma unroll
        for (int ct = 0; ct < 8; ct++) {
            int col = ct * 16 + l15;
            int m = sidx[col];
            const short* gfp = featT + ((size_t)(b * MPTS) + m) * CDIM;
            f32x4 lg = acc[rt][ct];
#pragma unroll
            for (int r = 0; r < 4; r++) {
                float v = lg[r];
                float mx = v;
                mx = fmaxf(mx, __shfl_xor(mx, 1));
                mx = fmaxf(mx, __shfl_xor(mx, 2));
                mx = fmaxf(mx, __shfl_xor(mx, 4));
                mx = fmaxf(mx, __shfl_xor(mx, 8));
                float e = __expf(v - mx);
                float s = e;
                s += __shfl_xor(s, 1);
                s += __shfl_xor(s, 2);
                s += __shfl_xor(s, 4);
                s += __shfl_xor(s, 8);
                int c = cb + r;
                float sv = b2f((unsigned short)gfp[c]) +
                           b2f(*(const unsigned short*)((const char*)pebuf + swz512(col, c * 2)));
                float o = (e / s) * sv;
                o += __shfl_xor(o, 1);
                o += __shfl_xor(o, 2);
                o += __shfl_xor(o, 4);
                o += __shfl_xor(o, 8);
                if (l15 == 0) out[((size_t)b * CDIM + c) * NPTS + n0 + ct] = o;
            }
        }
    }
}

// ------------------------------------------------------------------- launch
extern "C" void kernel_launch(void* const* d_in, const int* in_sizes, int n_in,
                              void* d_out, int out_size, void* d_ws, size_t ws_size,
                              hipStream_t stream) {
    const float* pcd    = (const float*)d_in[0];
    const float* feat   = (const float*)d_in[1];
    const float* pcddb  = (const float*)d_in[2];
    const float* featdb = (const float*)d_in[3];
    const float* pw1 = (const float*)d_in[4];
    const float* pb1 = (const float*)d_in[5];
    const float* pg  = (const float*)d_in[6];
    const float* pbe = (const float*)d_in[7];
    const float* pm  = (const float*)d_in[8];
    const float* pv  = (const float*)d_in[9];
    const float* pw2 = (const float*)d_in[10];
    const float* pb2 = (const float*)d_in[11];
    const float* aw1 = (const float*)d_in[12];
    const float* ab1 = (const float*)d_in[13];
    const float* ag  = (const float*)d_in[14];
    const float* abe = (const float*)d_in[15];
    const float* am  = (const float*)d_in[16];
    const float* av  = (const float*)d_in[17];
    const float* aw2 = (const float*)d_in[18];
    // d_in[19] = ab2: constant over k -> cancels in softmax, unused
    float* out = (float*)d_out;

    char* ws = (char*)d_ws;
    float* ws_r2  = (float*)ws;                          // 64 KB
    int*   ws_idx = (int*)(ws + 65536);                  // 512 KB
    short* aw1b   = (short*)(ws + 589824);               // 128 KB
    short* aw2b   = (short*)(ws + 720896);               // 128 KB
    short* pw2b   = (short*)(ws + 851968);               // 32 KB
    short* featT  = (short*)(ws + 884736);               // 8 MB
    float* ws_s   = (float*)(ws + 9273344);              // score chunk

    size_t fixed = 9273344;
    size_t avail = (ws_size > fixed) ? ws_size - fixed : 0;
    int chunk = 256;
    if (avail >= (size_t)2048 * 4096 * 4) chunk = 2048;
    else if (avail >= (size_t)1024 * 4096 * 4) chunk = 1024;
    else if (avail >= (size_t)512 * 4096 * 4) chunk = 512;

    wcvt<<<256, 256, 0, stream>>>(aw1, aw2, pw2, aw1b, aw2b, pw2b);
    tposeT<<<dim3(MPTS / 256, NB), 256, 0, stream>>>(feat, featdb, featT);
    r2_kernel<<<64, 256, 0, stream>>>(feat, featdb, ws_r2);
    for (int b = 0; b < NB; ++b) {
        for (int n0 = 0; n0 < NPTS; n0 += chunk) {
            dim3 g(chunk / 128, MPTS / 128);
            score_gemm<<<g, 256, 0, stream>>>(feat, featdb, ws_r2, ws_s, b, n0);
            topk16<<<chunk, 256, 0, stream>>>(ws_s, ws_idx, b, n0);
        }
    }
    fused_mlp2<<<NB * (NPTS / NPB), 512, 0, stream>>>(
        pcd, pcddb, featT, ws_idx,
        pw1, pb1, pg, pbe, pm, pv, pw2b, pb2,
        aw1b, ab1, ag, abe, am, av, aw2b, out);
}

// Round 3
// 402.372 us; speedup vs baseline: 3.8996x; 1.3678x over previous
//
#include <hip/hip_runtime.h>
#include <float.h>

#define CDIM 256
#define NPTS 2048
#define MPTS 4096
#define NB   4
#define KNN  16
#define COLS 64     // NPB(4) * KNN

typedef _Float16 half8 __attribute__((ext_vector_type(8)));
typedef _Float16 half4 __attribute__((ext_vector_type(4)));
typedef float    f32x4 __attribute__((ext_vector_type(4)));

// swizzled byte offsets: row stride 512B / 128B, XOR (row&7) into bits 4-6
__device__ __forceinline__ int swzS(int row, int byte) {
    return row * 512 + (byte ^ ((row & 7) << 4));
}
__device__ __forceinline__ int swz128(int row, int byte) {
    return row * 128 + (byte ^ ((row & 7) << 4));
}

// replace-max insertion into a register-resident top-16 (static indexing only)
#define INSERT16(dv, iv)                                                        \
    {                                                                           \
        int am = 0; float mv = td[0];                                           \
        _Pragma("unroll")                                                       \
        for (int i_ = 1; i_ < 16; i_++) { if (td[i_] > mv) { mv = td[i_]; am = i_; } } \
        _Pragma("unroll")                                                       \
        for (int i_ = 0; i_ < 16; i_++) if (am == i_) { td[i_] = (dv); ti[i_] = (iv); } \
        float nm = td[0];                                                       \
        _Pragma("unroll")                                                       \
        for (int i_ = 1; i_ < 16; i_++) nm = fmaxf(nm, td[i_]);                 \
        curmax = nm;                                                            \
    }

// ------- (B,C,M) fp32 -> featH/featL (B,M,C) f16 hi/lo + r2 (exact fp32)
__global__ __launch_bounds__(256) void tposeHL(const float* __restrict__ feat,
                                               const float* __restrict__ featdb,
                                               _Float16* __restrict__ featH,
                                               _Float16* __restrict__ featL,
                                               float* __restrict__ r2) {
    int b = blockIdx.y;
    int m = blockIdx.x * 256 + threadIdx.x;
    const float* src = (m < NPTS) ? (feat + (size_t)b * CDIM * NPTS + m)
                                  : (featdb + (size_t)b * CDIM * NPTS + (m - NPTS));
    _Float16* dh = featH + ((size_t)b * MPTS + m) * CDIM;
    _Float16* dl = featL + ((size_t)b * MPTS + m) * CDIM;
    float acc = 0.f;
    for (int c0 = 0; c0 < CDIM; c0 += 8) {
        half8 vh, vl;
#pragma unroll
        for (int i = 0; i < 8; i++) {
            float v = src[(size_t)(c0 + i) * NPTS];
            acc += v * v;
            _Float16 h = (_Float16)v;
            vh[i] = h;
            vl[i] = (_Float16)(v - (float)h);
        }
        *(half8*)(dh + c0) = vh;
        *(half8*)(dl + c0) = vl;
    }
    r2[b * MPTS + m] = acc;
}

// ------- weights fp32 -> f16
__global__ __launch_bounds__(256) void wcvt(const float* __restrict__ aw1,
                                            const float* __restrict__ aw2,
                                            const float* __restrict__ pw2,
                                            _Float16* __restrict__ aw1h,
                                            _Float16* __restrict__ aw2h,
                                            _Float16* __restrict__ pw2h) {
    int i = blockIdx.x * 256 + threadIdx.x;
    if (i < 65536) { aw1h[i] = (_Float16)aw1[i]; aw2h[i] = (_Float16)aw2[i]; }
    if (i < 16384) { pw2h[i] = (_Float16)pw2[i]; }
}

// ------- fused distance GEMM (fp16 hi/lo, 3-pass MFMA) + streaming top-16
// block = 4 waves x 16 queries = 64 queries, one m-quarter (1024 refs).
__global__ __launch_bounds__(256) void score_knn(const _Float16* __restrict__ featH,
                                                 const _Float16* __restrict__ featL,
                                                 const float* __restrict__ r2g,
                                                 float2* __restrict__ partial) {
    __shared__ __align__(16) char sbuf[32 * 512 * 2 + 256];
    _Float16* smH = (_Float16*)sbuf;
    _Float16* smL = (_Float16*)(sbuf + 16384);
    float* sr2 = (float*)(sbuf + 32768);

    const int tid = threadIdx.x;
    const int lane = tid & 63, wave = tid >> 6;
    const int l15 = lane & 15, l4 = lane >> 4;
    const int blk = blockIdx.x;          // ((b*32 + qt)*4) + quarter
    const int b = blk >> 7;
    const int qt = (blk >> 2) & 31;
    const int quarter = blk & 3;
    const int nq = qt * 64 + wave * 16 + l15;   // this lane's query (B-col)
    const int m0 = quarter * 1024;

    // query fragments (held in registers): 8 k-steps x {hi,lo}
    half8 qh[8], ql[8];
    {
        const _Float16* qb  = featH + ((size_t)b * MPTS + nq) * CDIM + l4 * 8;
        const _Float16* qlp = featL + ((size_t)b * MPTS + nq) * CDIM + l4 * 8;
#pragma unroll
        for (int ks = 0; ks < 8; ks++) {
            qh[ks] = *(const half8*)(qb + ks * 32);
            ql[ks] = *(const half8*)(qlp + ks * 32);
        }
    }

    float td[16]; int ti[16];
#pragma unroll
    for (int i = 0; i < 16; i++) { td[i] = FLT_MAX; ti[i] = 0x7fffffff; }
    float curmax = FLT_MAX;

    const int srow = tid >> 3;
    const int skc = (tid & 7) * 32;

    for (int s = 0; s < 32; ++s) {
        __syncthreads();
        {
            const _Float16* gh = featH + ((size_t)b * MPTS + m0 + s * 32 + srow) * CDIM + skc;
            const _Float16* gl = featL + ((size_t)b * MPTS + m0 + s * 32 + srow) * CDIM + skc;
#pragma unroll
            for (int j = 0; j < 4; j++) {
                *(half8*)((char*)smH + swzS(srow, (skc + j * 8) * 2)) = *(const half8*)(gh + j * 8);
                *(half8*)((char*)smL + swzS(srow, (skc + j * 8) * 2)) = *(const half8*)(gl + j * 8);
            }
        }
        if (tid < 32) sr2[tid] = r2g[b * MPTS + m0 + s * 32 + tid];
        __syncthreads();

#pragma unroll
        for (int sub = 0; sub < 2; ++sub) {
            f32x4 acc = {0.f, 0.f, 0.f, 0.f};
            int arow = sub * 16 + l15;
#pragma unroll
            for (int ks = 0; ks < 8; ks++) {
                int kb = (ks * 32 + l4 * 8) * 2;
                half8 ah = *(const half8*)((char*)smH + swzS(arow, kb));
                half8 al = *(const half8*)((char*)smL + swzS(arow, kb));
                acc = __builtin_amdgcn_mfma_f32_16x16x32_f16(ah, qh[ks], acc, 0, 0, 0);
                acc = __builtin_amdgcn_mfma_f32_16x16x32_f16(ah, ql[ks], acc, 0, 0, 0);
                acc = __builtin_amdgcn_mfma_f32_16x16x32_f16(al, qh[ks], acc, 0, 0, 0);
            }
#pragma unroll
            for (int r = 0; r < 4; r++) {
                int mloc = sub * 16 + 4 * l4 + r;
                float d = sr2[mloc] - 2.f * acc[r];
                if (d < curmax) INSERT16(d, m0 + s * 32 + mloc);
            }
        }
    }

    // merge the 4 l4-lanes of each query via LDS (reuse staging buffer)
    __syncthreads();
    float2* mb = (float2*)sbuf;
    {
        float2* dst = mb + wave * 1024 + l15 * 64 + l4 * 16;
#pragma unroll
        for (int e = 0; e < 16; e++) dst[e] = make_float2(td[e], __int_as_float(ti[e]));
    }
    __syncthreads();
    if (l4 == 0) {
        const float2* srcq = mb + wave * 1024 + l15 * 64;
        for (int e = 16; e < 64; e++) {
            float2 c = srcq[e];
            if (c.x < curmax) INSERT16(c.x, __float_as_int(c.y));
        }
        float2* o = partial + ((size_t)(b * NPTS + qt * 64 + wave * 16 + l15) * 4 + quarter) * 16;
#pragma unroll
        for (int e = 0; e < 16; e++) o[e] = make_float2(td[e], __int_as_float(ti[e]));
    }
}

// ------- final merge: 4 quarters x 16 -> top-16 per row
__global__ __launch_bounds__(256) void merge16(const float2* __restrict__ partial,
                                               int* __restrict__ idxout) {
    int row = blockIdx.x * 256 + threadIdx.x;
    float td[16]; int ti[16];
#pragma unroll
    for (int i = 0; i < 16; i++) { td[i] = FLT_MAX; ti[i] = 0x7fffffff; }
    float curmax = FLT_MAX;
    const float2* src = partial + (size_t)row * 64;
    for (int e = 0; e < 64; e++) {
        float2 c = src[e];
        if (c.x < curmax) INSERT16(c.x, __float_as_int(c.y));
    }
#pragma unroll
    for (int e = 0; e < 16; e++) idxout[row * 16 + e] = ti[e];
}

// ------- fused MLP chain on f16 MFMA. block = 4 points = 64 cols, 8 waves.
// ab2 dropped (constant over k -> cancels in softmax).
__global__ __launch_bounds__(512) void fused_mlp3(
    const float* __restrict__ pcd, const float* __restrict__ pcddb,
    const _Float16* __restrict__ featH, const int* __restrict__ knn,
    const float* __restrict__ pw1, const float* __restrict__ pb1,
    const float* __restrict__ pg, const float* __restrict__ pbe,
    const float* __restrict__ pm, const float* __restrict__ pv,
    const _Float16* __restrict__ pw2h, const float* __restrict__ pb2,
    const _Float16* __restrict__ aw1h, const float* __restrict__ ab1,
    const float* __restrict__ ag, const float* __restrict__ abe,
    const float* __restrict__ am, const float* __restrict__ av,
    const _Float16* __restrict__ aw2h,
    float* __restrict__ out) {
    __shared__ __align__(16) _Float16 xbuf[COLS * 256];    // 32 KB: x, then a1
    __shared__ __align__(16) _Float16 pebuf[COLS * 256];   // 32 KB
    __shared__ __align__(16) _Float16 hbuf[COLS * 64];     // 8 KB
    __shared__ __align__(16) float pr[3][COLS];
    __shared__ int sidx[COLS];
    __shared__ __align__(16) float ainv[256], ash2[256], pinv[64], psh[64];

    const int tid = threadIdx.x;
    const int lane = tid & 63, wave = tid >> 6;
    const int l15 = lane & 15, l4 = lane >> 4;
    const int blk = blockIdx.x;
    const int b = blk >> 9;
    const int n0 = (blk & 511) * 4;
    const int R0 = wave * 32;

    if (tid < COLS) {
        sidx[tid] = knn[(size_t)(b * NPTS + n0 + (tid >> 4)) * KNN + (tid & 15)];
    } else if (tid < COLS + 256) {
        int c = tid - COLS;
        float inv = ag[c] / sqrtf(av[c] + 1e-5f);
        ainv[c] = inv;
        ash2[c] = abe[c] - am[c] * inv + ab1[c] * inv;
    } else if (tid < COLS + 256 + 64) {
        int o = tid - COLS - 256;
        float inv = pg[o] / sqrtf(pv[o] + 1e-5f);
        pinv[o] = inv;
        psh[o] = pbe[o] - pm[o] * inv;
    }
    __syncthreads();

    if (tid < 3 * COLS) {
        int c = tid >> 6, col = tid & 63;
        int m = sidx[col];
        const float* pc = pcd + ((size_t)b * 3 + c) * NPTS;
        const float* px = pcddb + ((size_t)b * 3 + c) * NPTS;
        float gp = (m < NPTS) ? pc[m] : px[m - NPTS];
        pr[c][col] = pc[n0 + (col >> 4)] - gp;
    }
    __syncthreads();

    // h = relu(bn(pw1 @ pos_rel)) -> hbuf [col][64]
    {
        int col = tid >> 3, o0 = (tid & 7) * 8;
        float x0 = pr[0][col], x1 = pr[1][col], x2 = pr[2][col];
        half8 hv;
#pragma unroll
        for (int i = 0; i < 8; i++) {
            int o = o0 + i;
            float v = pw1[o * 3] * x0 + pw1[o * 3 + 1] * x1 + pw1[o * 3 + 2] * x2 + pb1[o];
            v = fmaxf(v * pinv[o] + psh[o], 0.f);
            hv[i] = (_Float16)v;
        }
        *(half8*)((char*)hbuf + swz128(col, o0 * 2)) = hv;
    }
    __syncthreads();

    f32x4 acc[2][4];
#pragma unroll
    for (int rt = 0; rt < 2; rt++)
#pragma unroll
        for (int ct = 0; ct < 4; ct++) acc[rt][ct] = (f32x4){0.f, 0.f, 0.f, 0.f};

    // pe GEMM: pw2 (256x64) @ h
#pragma unroll
    for (int ks = 0; ks < 2; ks++) {
        int k0 = ks * 32 + l4 * 8;
        half8 a0 = *(const half8*)(pw2h + (size_t)(R0 + l15) * 64 + k0);
        half8 a1 = *(const half8*)(pw2h + (size_t)(R0 + 16 + l15) * 64 + k0);
#pragma unroll
        for (int ct = 0; ct < 4; ct++) {
            half8 bb = *(const half8*)((char*)hbuf + swz128(ct * 16 + l15, k0 * 2));
            acc[0][ct] = __builtin_amdgcn_mfma_f32_16x16x32_f16(a0, bb, acc[0][ct], 0, 0, 0);
            acc[1][ct] = __builtin_amdgcn_mfma_f32_16x16x32_f16(a1, bb, acc[1][ct], 0, 0, 0);
        }
    }
#pragma unroll
    for (int rt = 0; rt < 2; rt++) {
        int cb = R0 + rt * 16 + 4 * l4;
        float4 pb = *(const float4*)(pb2 + cb);
        float pbv[4] = {pb.x, pb.y, pb.z, pb.w};
#pragma unroll
        for (int ct = 0; ct < 4; ct++) {
            int col = ct * 16 + l15;
            half4 p4;
#pragma unroll
            for (int r = 0; r < 4; r++) p4[r] = (_Float16)(acc[rt][ct][r] + pbv[r]);
            *(half4*)((char*)pebuf + swzS(col, cb * 2)) = p4;
        }
    }
    __syncthreads();

    // x = feat[n] - feat[m] + pe  -> xbuf [col][256]
    {
        int col = tid & 63, c0 = (tid >> 6) * 32;
        int m = sidx[col];
        const _Float16* fm = featH + ((size_t)b * MPTS + m) * CDIM;
        const _Float16* fn = featH + ((size_t)b * MPTS + n0 + (col >> 4)) * CDIM;
#pragma unroll
        for (int cc = 0; cc < 32; cc += 8) {
            int c = c0 + cc;
            half8 vm = *(const half8*)(fm + c);
            half8 vn = *(const half8*)(fn + c);
            half8 vp = *(const half8*)((char*)pebuf + swzS(col, c * 2));
            half8 xv;
#pragma unroll
            for (int i = 0; i < 8; i++)
                xv[i] = (_Float16)((float)vn[i] - (float)vm[i] + (float)vp[i]);
            *(half8*)((char*)xbuf + swzS(col, c * 2)) = xv;
        }
    }
    __syncthreads();

    // GEMM1: aw1 @ x
#pragma unroll
    for (int rt = 0; rt < 2; rt++)
#pragma unroll
        for (int ct = 0; ct < 4; ct++) acc[rt][ct] = (f32x4){0.f, 0.f, 0.f, 0.f};
#pragma unroll
    for (int ks = 0; ks < 8; ks++) {
        int k0 = ks * 32 + l4 * 8;
        half8 a0 = *(const half8*)(aw1h + (size_t)(R0 + l15) * 256 + k0);
        half8 a1 = *(const half8*)(aw1h + (size_t)(R0 + 16 + l15) * 256 + k0);
#pragma unroll
        for (int ct = 0; ct < 4; ct++) {
            half8 bb = *(const half8*)((char*)xbuf + swzS(ct * 16 + l15, k0 * 2));
            acc[0][ct] = __builtin_amdgcn_mfma_f32_16x16x32_f16(a0, bb, acc[0][ct], 0, 0, 0);
            acc[1][ct] = __builtin_amdgcn_mfma_f32_16x16x32_f16(a1, bb, acc[1][ct], 0, 0, 0);
        }
    }
    __syncthreads();
    // a1 = relu(bn(.)) -> xbuf (packed 8-B writes)
#pragma unroll
    for (int rt = 0; rt < 2; rt++) {
        int cb = R0 + rt * 16 + 4 * l4;
        float4 iv = *(const float4*)(&ainv[cb]);
        float4 sh = *(const float4*)(&ash2[cb]);
        float ivv[4] = {iv.x, iv.y, iv.z, iv.w};
        float shv[4] = {sh.x, sh.y, sh.z, sh.w};
#pragma unroll
        for (int ct = 0; ct < 4; ct++) {
            int col = ct * 16 + l15;
            half4 h4;
#pragma unroll
            for (int r = 0; r < 4; r++)
                h4[r] = (_Float16)fmaxf(acc[rt][ct][r] * ivv[r] + shv[r], 0.f);
            *(half4*)((char*)xbuf + swzS(col, cb * 2)) = h4;
        }
    }
    __syncthreads();

    // GEMM2: aw2 @ a1
#pragma unroll
    for (int rt = 0; rt < 2; rt++)
#pragma unroll
        for (int ct = 0; ct < 4; ct++) acc[rt][ct] = (f32x4){0.f, 0.f, 0.f, 0.f};
#pragma unroll
    for (int ks = 0; ks < 8; ks++) {
        int k0 = ks * 32 + l4 * 8;
        half8 a0 = *(const half8*)(aw2h + (size_t)(R0 + l15) * 256 + k0);
        half8 a1 = *(const half8*)(aw2h + (size_t)(R0 + 16 + l15) * 256 + k0);
#pragma unroll
        for (int ct = 0; ct < 4; ct++) {
            half8 bb = *(const half8*)((char*)xbuf + swzS(ct * 16 + l15, k0 * 2));
            acc[0][ct] = __builtin_amdgcn_mfma_f32_16x16x32_f16(a0, bb, acc[0][ct], 0, 0, 0);
            acc[1][ct] = __builtin_amdgcn_mfma_f32_16x16x32_f16(a1, bb, acc[1][ct], 0, 0, 0);
        }
    }

    // softmax over 16 lanes (k) + weighted sum
#pragma unroll
    for (int rt = 0; rt < 2; rt++) {
        int cb = R0 + rt * 16 + 4 * l4;
#pragma unroll
        for (int ct = 0; ct < 4; ct++) {
            int col = ct * 16 + l15;
            int m = sidx[col];
            half4 gf4 = *(const half4*)(featH + ((size_t)b * MPTS + m) * CDIM + cb);
            half4 pe4 = *(const half4*)((char*)pebuf + swzS(col, cb * 2));
#pragma unroll
            for (int r = 0; r < 4; r++) {
                float v = acc[rt][ct][r];
                float mx = v;
                mx = fmaxf(mx, __shfl_xor(mx, 1));
                mx = fmaxf(mx, __shfl_xor(mx, 2));
                mx = fmaxf(mx, __shfl_xor(mx, 4));
                mx = fmaxf(mx, __shfl_xor(mx, 8));
                float e = __expf(v - mx);
                float s = e;
                s += __shfl_xor(s, 1);
                s += __shfl_xor(s, 2);
                s += __shfl_xor(s, 4);
                s += __shfl_xor(s, 8);
                float sv = (float)gf4[r] + (float)pe4[r];
                float o = e * sv;
                o += __shfl_xor(o, 1);
                o += __shfl_xor(o, 2);
                o += __shfl_xor(o, 4);
                o += __shfl_xor(o, 8);
                if (l15 == 0) out[((size_t)b * CDIM + cb + r) * NPTS + n0 + ct] = o / s;
            }
        }
    }
}

// ------------------------------------------------------------------- launch
extern "C" void kernel_launch(void* const* d_in, const int* in_sizes, int n_in,
                              void* d_out, int out_size, void* d_ws, size_t ws_size,
                              hipStream_t stream) {
    const float* pcd    = (const float*)d_in[0];
    const float* feat   = (const float*)d_in[1];
    const float* pcddb  = (const float*)d_in[2];
    const float* featdb = (const float*)d_in[3];
    const float* pw1 = (const float*)d_in[4];
    const float* pb1 = (const float*)d_in[5];
    const float* pg  = (const float*)d_in[6];
    const float* pbe = (const float*)d_in[7];
    const float* pm  = (const float*)d_in[8];
    const float* pv  = (const float*)d_in[9];
    const float* pw2 = (const float*)d_in[10];
    const float* pb2 = (const float*)d_in[11];
    const float* aw1 = (const float*)d_in[12];
    const float* ab1 = (const float*)d_in[13];
    const float* ag  = (const float*)d_in[14];
    const float* abe = (const float*)d_in[15];
    const float* am  = (const float*)d_in[16];
    const float* av  = (const float*)d_in[17];
    const float* aw2 = (const float*)d_in[18];
    // d_in[19] = ab2: constant over k -> cancels in softmax, unused
    float* out = (float*)d_out;

    char* ws = (char*)d_ws;
    _Float16* featH   = (_Float16*)(ws);               // 8 MB
    _Float16* featL   = (_Float16*)(ws + 8388608);     // 8 MB
    float*    ws_r2   = (float*)(ws + 16777216);       // 64 KB
    float2*   partial = (float2*)(ws + 16842752);      // 4 MB
    int*      ws_idx  = (int*)(ws + 21037056);         // 512 KB
    _Float16* aw1h    = (_Float16*)(ws + 21561344);    // 128 KB
    _Float16* aw2h    = (_Float16*)(ws + 21692416);    // 128 KB
    _Float16* pw2h    = (_Float16*)(ws + 21823488);    // 32 KB

    wcvt<<<256, 256, 0, stream>>>(aw1, aw2, pw2, aw1h, aw2h, pw2h);
    tposeHL<<<dim3(MPTS / 256, NB), 256, 0, stream>>>(feat, featdb, featH, featL, ws_r2);
    score_knn<<<NB * 32 * 4, 256, 0, stream>>>(featH, featL, ws_r2, partial);
    merge16<<<NB * NPTS / 256, 256, 0, stream>>>(partial, ws_idx);
    fused_mlp3<<<NB * (NPTS / 4), 512, 0, stream>>>(
        pcd, pcddb, featH, ws_idx,
        pw1, pb1, pg, pbe, pm, pv, pw2h, pb2,
        aw1h, ab1, ag, abe, am, av, aw2h, out);
}